// Round 1
// baseline (665.546 us; speedup 1.0000x reference)
//
#include <hip/hip_runtime.h>
#include <stdint.h>

// WordLSTMCell: c1 = sigmoid(f)*c0 + sigmoid(i)*tanh(c),
//   [f|i|c] = x@W + h@Wh + b ;  x:[8192,1024] h,c0:[8192,2048]
//   W:[1024,6144] Wh:[2048,6144] b:[6144]  (all fp32; out fp32 [8192,2048])
//
// Design: one fused bf16-MFMA GEMM, M=8192 K=3072 (concat x,h), per-block
// output tile 128 rows x 64 cols, accumulating BN=192 gate columns
// (f,i,c blocks at j, 2048+j, 4096+j). Wave layout chosen so each wave holds
// matching f/i/c fragments for the same output columns -> register-only epilogue.
// Path A (ws >= 84MB): pack bf16 A[ktile][m][32] and B^T[ktile][n][32], GEMM
// stages via global_load_lds width=16 (conflict-free 64B LDS rows).
// Path B (small ws): fused fp32->bf16 staging in registers (padded LDS rows).

#define BATCH 8192
#define INSZ  1024
#define HID   2048
#define NG    6144
#define KTOT  3072
#define KTILES 96

typedef __attribute__((ext_vector_type(8))) short short8;
typedef __attribute__((ext_vector_type(4))) short short4v;
typedef __attribute__((ext_vector_type(4))) float f32x4;
typedef __attribute__((ext_vector_type(4))) unsigned short u16x4;
typedef __attribute__((ext_vector_type(8))) unsigned short u16x8;

__device__ __forceinline__ unsigned short f32_to_bf16(float f) {
  uint32_t u = __builtin_bit_cast(uint32_t, f);
  u += 0x7fffu + ((u >> 16) & 1u);   // round-to-nearest-even
  return (unsigned short)(u >> 16);
}

// ---------------- pack kernels (Path A) ----------------

// Apack[kt][m][kk] = concat(x,h)[m][kt*32+kk], bf16. 48 MB.
__global__ __launch_bounds__(256) void pack_a_kernel(
    const float* __restrict__ x, const float* __restrict__ h,
    unsigned short* __restrict__ Ap) {
  uint32_t q   = blockIdx.x * 256u + threadIdx.x;  // [0, 96*8192*8)
  uint32_t kk4 = q & 7u;
  uint32_t m   = (q >> 3) & 8191u;
  uint32_t kt  = q >> 16;
  uint32_t k   = kt * 32u + kk4 * 4u;
  const float* src = (k < INSZ) ? (x + (size_t)m * INSZ + k)
                                : (h + (size_t)m * HID + (k - INSZ));
  float4 v = *(const float4*)src;
  u16x4 o;
  o.x = f32_to_bf16(v.x); o.y = f32_to_bf16(v.y);
  o.z = f32_to_bf16(v.z); o.w = f32_to_bf16(v.w);
  *(u16x4*)(Ap + ((size_t)kt * BATCH + m) * 32 + kk4 * 4) = o;
}

// Bpack[kt][n][kk] = vstack(W,Wh)[kt*32+kk][n], bf16 (transpose). 36 MB.
__global__ __launch_bounds__(256) void pack_b_kernel(
    const float* __restrict__ W, const float* __restrict__ Wh,
    unsigned short* __restrict__ Bp) {
  __shared__ unsigned short tile[128 * 34];  // pad stride 34 to spread banks
  const uint32_t kt = blockIdx.x / 48u;
  const uint32_t nt = blockIdx.x % 48u;
  const uint32_t k0 = kt * 32u, n0 = nt * 128u;
#pragma unroll
  for (int i = 0; i < 4; ++i) {
    uint32_t p  = i * 256u + threadIdx.x;   // 1024 float4 tasks
    uint32_t kk = p >> 5;
    uint32_t n4 = (p & 31u) * 4u;
    uint32_t k  = k0 + kk;
    const float* src = (k < INSZ) ? (W + (size_t)k * NG + n0 + n4)
                                  : (Wh + (size_t)(k - INSZ) * NG + n0 + n4);
    float4 v = *(const float4*)src;
    tile[(n4 + 0) * 34 + kk] = f32_to_bf16(v.x);
    tile[(n4 + 1) * 34 + kk] = f32_to_bf16(v.y);
    tile[(n4 + 2) * 34 + kk] = f32_to_bf16(v.z);
    tile[(n4 + 3) * 34 + kk] = f32_to_bf16(v.w);
  }
  __syncthreads();
#pragma unroll
  for (int i = 0; i < 2; ++i) {
    uint32_t p = i * 256u + threadIdx.x;    // 512 x 16B out
    uint32_t n = p >> 2, u = p & 3u;
    u16x8 val;
#pragma unroll
    for (int j = 0; j < 8; ++j) val[j] = tile[n * 34 + u * 8 + j];
    *(u16x8*)(Bp + ((size_t)kt * NG + n0 + n) * 32 + u * 8) = val;
  }
}

// ---------------- shared epilogue ----------------
// C-layout (m89-verified): col = lane&15, row = (lane>>4)*4 + reg.
__device__ __forceinline__ void lstm_epilogue(
    const f32x4 acc[4][6], int m0, int j0, int wm, int wn, int quad, int l16,
    const float* __restrict__ bias, const float* __restrict__ c0,
    float* __restrict__ out) {
#pragma unroll
  for (int mi = 0; mi < 4; ++mi) {
    int rowb = m0 + wm * 64 + mi * 16 + quad * 4;
#pragma unroll
    for (int p = 0; p < 2; ++p) {
      int j = j0 + (2 * wn + p) * 16 + l16;
      float bfv = bias[j], biv = bias[HID + j], bcv = bias[2 * HID + j];
#pragma unroll
      for (int r = 0; r < 4; ++r) {
        size_t idx = (size_t)(rowb + r) * HID + j;
        float fg = acc[mi][0 + p][r] + bfv;
        float ig = acc[mi][2 + p][r] + biv;
        float cg = acc[mi][4 + p][r] + bcv;
        float sf = 1.f / (1.f + __expf(-fg));
        float si = 1.f / (1.f + __expf(-ig));
        float th = 2.f / (1.f + __expf(-2.f * cg)) - 1.f;
        out[idx] = sf * c0[idx] + si * th;
      }
    }
  }
}

// ---------------- Path A GEMM: packed bf16 + global_load_lds ----------------
__global__ __launch_bounds__(256) void gemm_packed_kernel(
    const unsigned short* __restrict__ Ap, const unsigned short* __restrict__ Bp,
    const float* __restrict__ bias, const float* __restrict__ c0,
    float* __restrict__ out) {
  __shared__ __align__(16) unsigned short As[128 * 32];  // 8 KB, 64B rows
  __shared__ __align__(16) unsigned short Bs[192 * 32];  // 12 KB
  const int tid = threadIdx.x;
  const int lane = tid & 63, w = tid >> 6;
  const int wm = w >> 1, wn = w & 1;       // waves 2(M) x 2(N-pairs)
  const int quad = lane >> 4, l16 = lane & 15;
  const int bx = blockIdx.x;
  const int jt = bx & 31, mt = bx >> 5;
  const int m0 = mt * 128, j0 = jt * 64;

  f32x4 acc[4][6];
#pragma unroll
  for (int a = 0; a < 4; ++a)
#pragma unroll
    for (int b = 0; b < 6; ++b) acc[a][b] = (f32x4){0.f, 0.f, 0.f, 0.f};

  for (int kt = 0; kt < KTILES; ++kt) {
    const unsigned short* ga = Ap + ((size_t)kt * BATCH + m0) * 32;
#pragma unroll
    for (int i = 0; i < 2; ++i) {           // A: 8 x 1KB wave-loads
      int t2 = w * 2 + i;
      __builtin_amdgcn_global_load_lds(
          (__attribute__((address_space(1))) void*)(void*)(ga + t2 * 512 + lane * 8),
          (__attribute__((address_space(3))) void*)(As + t2 * 512), 16, 0, 0);
    }
#pragma unroll
    for (int i = 0; i < 3; ++i) {           // B: 12 x 1KB wave-loads
      int t = w * 3 + i;
      int g = t >> 2, sub = t & 3;
      const unsigned short* gb =
          Bp + ((size_t)kt * NG + g * HID + j0 + sub * 16) * 32;
      __builtin_amdgcn_global_load_lds(
          (__attribute__((address_space(1))) void*)(void*)(gb + lane * 8),
          (__attribute__((address_space(3))) void*)(Bs + t * 512), 16, 0, 0);
    }
    __syncthreads();
    short8 af[4], bf[6];
#pragma unroll
    for (int mi = 0; mi < 4; ++mi)  // A-frag: A[m=l16][k=quad*8+j]
      af[mi] = *(const short8*)(As + (wm * 64 + mi * 16 + l16) * 32 + quad * 8);
#pragma unroll
    for (int g = 0; g < 3; ++g)     // B-frag: B[k=quad*8+j][n=l16]
#pragma unroll
      for (int p = 0; p < 2; ++p)
        bf[g * 2 + p] = *(const short8*)(
            Bs + (g * 64 + (2 * wn + p) * 16 + l16) * 32 + quad * 8);
#pragma unroll
    for (int mi = 0; mi < 4; ++mi)
#pragma unroll
      for (int f = 0; f < 6; ++f)
        acc[mi][f] =
            __builtin_amdgcn_mfma_f32_16x16x32_bf16(af[mi], bf[f], acc[mi][f], 0, 0, 0);
    __syncthreads();
  }
  lstm_epilogue(acc, m0, j0, wm, wn, quad, l16, bias, c0, out);
}

// ---------------- Path B GEMM: fp32 staging fallback (no workspace) --------
__global__ __launch_bounds__(256) void gemm_f32_kernel(
    const float* __restrict__ x, const float* __restrict__ h,
    const float* __restrict__ W, const float* __restrict__ Wh,
    const float* __restrict__ bias, const float* __restrict__ c0,
    float* __restrict__ out) {
  __shared__ __align__(16) unsigned short As[128 * 36];  // 72B rows (pad)
  __shared__ __align__(16) unsigned short Bs[192 * 36];
  const int tid = threadIdx.x;
  const int lane = tid & 63, w = tid >> 6;
  const int wm = w >> 1, wn = w & 1;
  const int quad = lane >> 4, l16 = lane & 15;
  const int bx = blockIdx.x;
  const int jt = bx & 31, mt = bx >> 5;
  const int m0 = mt * 128, j0 = jt * 64;

  f32x4 acc[4][6];
#pragma unroll
  for (int a = 0; a < 4; ++a)
#pragma unroll
    for (int b = 0; b < 6; ++b) acc[a][b] = (f32x4){0.f, 0.f, 0.f, 0.f};

  for (int kt = 0; kt < KTILES; ++kt) {
    int k0 = kt * 32;
#pragma unroll
    for (int i = 0; i < 4; ++i) {   // A: coalesced float4 along k, b64 LDS write
      int q = i * 256 + tid;
      int m = q >> 3, kk = (q & 7) * 4;
      int k = k0 + kk;
      const float* src = (k < INSZ) ? (x + (size_t)(m0 + m) * INSZ + k)
                                    : (h + (size_t)(m0 + m) * HID + (k - INSZ));
      float4 v = *(const float4*)src;
      u16x4 o;
      o.x = f32_to_bf16(v.x); o.y = f32_to_bf16(v.y);
      o.z = f32_to_bf16(v.z); o.w = f32_to_bf16(v.w);
      *(u16x4*)(As + m * 36 + kk) = o;
    }
#pragma unroll
    for (int i = 0; i < 6; ++i) {   // B: 4 k-strided dword loads (lane-coalesced in n)
      int q = i * 256 + tid;
      int n = q % 192, kq = (q / 192) * 4;
      int col = (n >> 6) * HID + j0 + (n & 63);
      float vv[4];
#pragma unroll
      for (int t = 0; t < 4; ++t) {
        int k = k0 + kq + t;
        vv[t] = (k < INSZ) ? W[(size_t)k * NG + col]
                           : Wh[(size_t)(k - INSZ) * NG + col];
      }
      u16x4 o;
      o.x = f32_to_bf16(vv[0]); o.y = f32_to_bf16(vv[1]);
      o.z = f32_to_bf16(vv[2]); o.w = f32_to_bf16(vv[3]);
      *(u16x4*)(Bs + n * 36 + kq) = o;
    }
    __syncthreads();
    short8 af[4], bf[6];
#pragma unroll
    for (int mi = 0; mi < 4; ++mi) {
      int base = (wm * 64 + mi * 16 + l16) * 36 + quad * 8;
      short4v lo = *(const short4v*)(As + base);
      short4v hi = *(const short4v*)(As + base + 4);
      af[mi] = __builtin_shufflevector(lo, hi, 0, 1, 2, 3, 4, 5, 6, 7);
    }
#pragma unroll
    for (int g = 0; g < 3; ++g)
#pragma unroll
      for (int p = 0; p < 2; ++p) {
        int base = (g * 64 + (2 * wn + p) * 16 + l16) * 36 + quad * 8;
        short4v lo = *(const short4v*)(Bs + base);
        short4v hi = *(const short4v*)(Bs + base + 4);
        bf[g * 2 + p] = __builtin_shufflevector(lo, hi, 0, 1, 2, 3, 4, 5, 6, 7);
      }
#pragma unroll
    for (int mi = 0; mi < 4; ++mi)
#pragma unroll
      for (int f = 0; f < 6; ++f)
        acc[mi][f] =
            __builtin_amdgcn_mfma_f32_16x16x32_bf16(af[mi], bf[f], acc[mi][f], 0, 0, 0);
    __syncthreads();
  }
  lstm_epilogue(acc, m0, j0, wm, wn, quad, l16, bias, c0, out);
}

extern "C" void kernel_launch(void* const* d_in, const int* in_sizes, int n_in,
                              void* d_out, int out_size, void* d_ws, size_t ws_size,
                              hipStream_t stream) {
  const float* x    = (const float*)d_in[0];
  const float* h0   = (const float*)d_in[1];
  const float* c0   = (const float*)d_in[2];
  const float* W    = (const float*)d_in[3];
  const float* Wh   = (const float*)d_in[4];
  const float* bias = (const float*)d_in[5];
  float* out = (float*)d_out;

  const size_t needA = (size_t)KTOT * BATCH * 2;  // 48 MB
  const size_t needB = (size_t)KTOT * NG * 2;     // 36 MB
  if (ws_size >= needA + needB) {
    unsigned short* Ap = (unsigned short*)d_ws;
    unsigned short* Bp = Ap + (size_t)KTOT * BATCH;
    pack_a_kernel<<<24576, 256, 0, stream>>>(x, h0, Ap);
    pack_b_kernel<<<4608, 256, 0, stream>>>(W, Wh, Bp);
    gemm_packed_kernel<<<2048, 256, 0, stream>>>(Ap, Bp, bias, c0, out);
  } else {
    gemm_f32_kernel<<<2048, 256, 0, stream>>>(x, h0, W, Wh, bias, c0, out);
  }
}

// Round 2
// 636.006 us; speedup vs baseline: 1.0464x; 1.0464x over previous
//
#include <hip/hip_runtime.h>
#include <stdint.h>

// WordLSTMCell: c1 = sigmoid(f)*c0 + sigmoid(i)*tanh(c),
//   [f|i|c] = x@W + h@Wh + b ;  x:[8192,1024] h,c0:[8192,2048]
//   W:[1024,6144] Wh:[2048,6144] b:[6144]  (all fp32; out fp32 [8192,2048])
//
// Round 2: LDS read pipe was the bottleneck (ds_reads ~= MFMA cycles, +10%
// bank conflicts). Changes:
//  - B fragments stream register-direct from packed global (no LDS for B),
//    double-buffered across kt (prefetch kt+1 after the top barrier).
//  - A stays in LDS via global_load_lds, but rows are XOR-swizzled
//    (chunk c -> c ^ ((m + (m>>2)) & 3)), baked into Ap's global layout,
//    so b128 frag reads are 2-way-max on banks (free).
//  - pack_b rewritten without LDS (strided reads, coalesced stores).
//  - block swizzle: co-resident blocks share the streamed B slice in L2.

#define BATCH 8192
#define INSZ  1024
#define HID   2048
#define NG    6144
#define KTOT  3072
#define KTILES 96

typedef __attribute__((ext_vector_type(8))) short short8;
typedef __attribute__((ext_vector_type(4))) short short4v;
typedef __attribute__((ext_vector_type(4))) float f32x4;
typedef __attribute__((ext_vector_type(4))) unsigned short u16x4;

__device__ __forceinline__ unsigned short f32_to_bf16(float f) {
  uint32_t u = __builtin_bit_cast(uint32_t, f);
  u += 0x7fffu + ((u >> 16) & 1u);   // round-to-nearest-even
  return (unsigned short)(u >> 16);
}

// ---------------- pack kernels (Path A) ----------------

// Apack[kt][m][chunk-swizzled 32] = concat(x,h)[m][kt*32+..], bf16. 48 MB.
// Within each 64B row, 16B chunk c stored at c ^ ((m + (m>>2)) & 3).
__global__ __launch_bounds__(256) void pack_a_kernel(
    const float* __restrict__ x, const float* __restrict__ h,
    unsigned short* __restrict__ Ap) {
  uint32_t q   = blockIdx.x * 256u + threadIdx.x;  // [0, 96*8192*8)
  uint32_t kk4 = q & 7u;           // half-chunk index (4 floats)
  uint32_t m   = (q >> 3) & 8191u;
  uint32_t kt  = q >> 16;
  uint32_t k   = kt * 32u + kk4 * 4u;
  const float* src = (k < INSZ) ? (x + (size_t)m * INSZ + k)
                                : (h + (size_t)m * HID + (k - INSZ));
  float4 v = *(const float4*)src;
  u16x4 o;
  o.x = f32_to_bf16(v.x); o.y = f32_to_bf16(v.y);
  o.z = f32_to_bf16(v.z); o.w = f32_to_bf16(v.w);
  uint32_t c  = kk4 >> 1, hh = kk4 & 1;
  uint32_t sm = (m + (m >> 2)) & 3u;
  *(u16x4*)(Ap + ((size_t)kt * BATCH + m) * 32 + ((c ^ sm) * 8 + hh * 4)) = o;
}

// Bpack[kt][n][kk] = vstack(W,Wh)[kt*32+kk][n], bf16. 36 MB. No LDS:
// strided reads (8x32B segments/wave), fully coalesced 8B stores.
__global__ __launch_bounds__(256) void pack_b_kernel(
    const float* __restrict__ W, const float* __restrict__ Wh,
    unsigned short* __restrict__ Bp) {
  uint32_t q  = blockIdx.x * 256u + threadIdx.x;  // [0, 96*6144*8)
  uint32_t hh = q & 7u;                            // u16x4 within row
  uint32_t r  = q >> 3;
  uint32_t n  = r % 6144u;
  uint32_t kt = r / 6144u;
  uint32_t k0 = kt * 32u + hh * 4u;
  float v[4];
#pragma unroll
  for (int t = 0; t < 4; ++t) {
    uint32_t k = k0 + t;
    v[t] = (k < INSZ) ? W[(size_t)k * NG + n]
                      : Wh[(size_t)(k - INSZ) * NG + n];
  }
  u16x4 o;
  o.x = f32_to_bf16(v[0]); o.y = f32_to_bf16(v[1]);
  o.z = f32_to_bf16(v[2]); o.w = f32_to_bf16(v[3]);
  *(u16x4*)(Bp + ((size_t)kt * NG + n) * 32 + hh * 4) = o;
}

// ---------------- shared epilogue ----------------
// C-layout (m89-verified): col = lane&15, row = (lane>>4)*4 + reg.
__device__ __forceinline__ void lstm_epilogue(
    const f32x4 acc[4][6], int m0, int j0, int wm, int wn, int quad, int l16,
    const float* __restrict__ bias, const float* __restrict__ c0,
    float* __restrict__ out) {
#pragma unroll
  for (int mi = 0; mi < 4; ++mi) {
    int rowb = m0 + wm * 64 + mi * 16 + quad * 4;
#pragma unroll
    for (int p = 0; p < 2; ++p) {
      int j = j0 + (2 * wn + p) * 16 + l16;
      float bfv = bias[j], biv = bias[HID + j], bcv = bias[2 * HID + j];
#pragma unroll
      for (int r = 0; r < 4; ++r) {
        size_t idx = (size_t)(rowb + r) * HID + j;
        float fg = acc[mi][0 + p][r] + bfv;
        float ig = acc[mi][2 + p][r] + biv;
        float cg = acc[mi][4 + p][r] + bcv;
        float sf = 1.f / (1.f + __expf(-fg));
        float si = 1.f / (1.f + __expf(-ig));
        float th = 2.f / (1.f + __expf(-2.f * cg)) - 1.f;
        out[idx] = sf * c0[idx] + si * th;
      }
    }
  }
}

// ---------------- Path A GEMM: A via LDS (swizzled), B register-direct ----
__global__ __launch_bounds__(256) void gemm_packed_kernel(
    const unsigned short* __restrict__ Ap, const unsigned short* __restrict__ Bp,
    const float* __restrict__ bias, const float* __restrict__ c0,
    float* __restrict__ out) {
  __shared__ __align__(16) unsigned short As[128 * 32];  // 8 KB, swizzled rows
  const int tid = threadIdx.x;
  const int lane = tid & 63, w = tid >> 6;
  const int wm = w >> 1, wn = w & 1;       // waves 2(M) x 2(N-pairs)
  const int quad = lane >> 4, l16 = lane & 15;
  const int bx = blockIdx.x;
  const int mt = bx & 63, jt = bx >> 6;    // co-resident blocks share jt (B slice)
  const int m0 = mt * 128, j0 = jt * 64;
  const int sw = (l16 + (l16 >> 2)) & 3;   // A-row bank swizzle (uniform in mi)

  f32x4 acc[4][6];
#pragma unroll
  for (int a = 0; a < 4; ++a)
#pragma unroll
    for (int b = 0; b < 6; ++b) acc[a][b] = (f32x4){0.f, 0.f, 0.f, 0.f};

  // B fragment base: frag(g,p) at bb + kt*NG*32 + g*(HID*32) + p*512 (shorts)
  const unsigned short* bb =
      Bp + ((size_t)(j0 + 2 * wn * 16 + l16)) * 32 + quad * 8;

  short8 bf[2][6];
#pragma unroll
  for (int g = 0; g < 3; ++g)
#pragma unroll
    for (int p = 0; p < 2; ++p)
      bf[0][g * 2 + p] = *(const short8*)(bb + g * (HID * 32) + p * 512);

#pragma unroll 2
  for (int kt = 0; kt < KTILES; ++kt) {
    const int cur = kt & 1;
    const unsigned short* ga = Ap + ((size_t)kt * BATCH + m0) * 32;
#pragma unroll
    for (int i = 0; i < 2; ++i) {           // A: 8 x 1KB wave-loads
      int t2 = w * 2 + i;
      __builtin_amdgcn_global_load_lds(
          (__attribute__((address_space(1))) void*)(void*)(ga + t2 * 512 + lane * 8),
          (__attribute__((address_space(3))) void*)(As + t2 * 512), 16, 0, 0);
    }
    __syncthreads();                        // drains A-lds(kt) and bf[cur]
    // prefetch next-kt B frags: fly across ds_reads + MFMAs
    if (kt + 1 < KTILES) {
      const unsigned short* bn = bb + (size_t)(kt + 1) * (NG * 32);
#pragma unroll
      for (int g = 0; g < 3; ++g)
#pragma unroll
        for (int p = 0; p < 2; ++p)
          bf[cur ^ 1][g * 2 + p] = *(const short8*)(bn + g * (HID * 32) + p * 512);
    }
    short8 af[4];
#pragma unroll
    for (int mi = 0; mi < 4; ++mi)  // A-frag: A[m=l16][k=quad*8+j], de-swizzled
      af[mi] = *(const short8*)(
          As + (wm * 64 + mi * 16 + l16) * 32 + ((quad ^ sw) * 8));
#pragma unroll
    for (int mi = 0; mi < 4; ++mi)
#pragma unroll
      for (int f = 0; f < 6; ++f)
        acc[mi][f] =
            __builtin_amdgcn_mfma_f32_16x16x32_bf16(af[mi], bf[cur][f], acc[mi][f], 0, 0, 0);
    __syncthreads();
  }
  lstm_epilogue(acc, m0, j0, wm, wn, quad, l16, bias, c0, out);
}

// ---------------- Path B GEMM: fp32 staging fallback (no workspace) --------
__global__ __launch_bounds__(256) void gemm_f32_kernel(
    const float* __restrict__ x, const float* __restrict__ h,
    const float* __restrict__ W, const float* __restrict__ Wh,
    const float* __restrict__ bias, const float* __restrict__ c0,
    float* __restrict__ out) {
  __shared__ __align__(16) unsigned short As[128 * 36];  // 72B rows (pad)
  __shared__ __align__(16) unsigned short Bs[192 * 36];
  const int tid = threadIdx.x;
  const int lane = tid & 63, w = tid >> 6;
  const int wm = w >> 1, wn = w & 1;
  const int quad = lane >> 4, l16 = lane & 15;
  const int bx = blockIdx.x;
  const int jt = bx & 31, mt = bx >> 5;
  const int m0 = mt * 128, j0 = jt * 64;

  f32x4 acc[4][6];
#pragma unroll
  for (int a = 0; a < 4; ++a)
#pragma unroll
    for (int b = 0; b < 6; ++b) acc[a][b] = (f32x4){0.f, 0.f, 0.f, 0.f};

  for (int kt = 0; kt < KTILES; ++kt) {
    int k0 = kt * 32;
#pragma unroll
    for (int i = 0; i < 4; ++i) {
      int q = i * 256 + tid;
      int m = q >> 3, kk = (q & 7) * 4;
      int k = k0 + kk;
      const float* src = (k < INSZ) ? (x + (size_t)(m0 + m) * INSZ + k)
                                    : (h + (size_t)(m0 + m) * HID + (k - INSZ));
      float4 v = *(const float4*)src;
      u16x4 o;
      o.x = f32_to_bf16(v.x); o.y = f32_to_bf16(v.y);
      o.z = f32_to_bf16(v.z); o.w = f32_to_bf16(v.w);
      *(u16x4*)(As + m * 36 + kk) = o;
    }
#pragma unroll
    for (int i = 0; i < 6; ++i) {
      int q = i * 256 + tid;
      int n = q % 192, kq = (q / 192) * 4;
      int col = (n >> 6) * HID + j0 + (n & 63);
      float vv[4];
#pragma unroll
      for (int t = 0; t < 4; ++t) {
        int k = k0 + kq + t;
        vv[t] = (k < INSZ) ? W[(size_t)k * NG + col]
                           : Wh[(size_t)(k - INSZ) * NG + col];
      }
      u16x4 o;
      o.x = f32_to_bf16(vv[0]); o.y = f32_to_bf16(vv[1]);
      o.z = f32_to_bf16(vv[2]); o.w = f32_to_bf16(vv[3]);
      *(u16x4*)(Bs + n * 36 + kq) = o;
    }
    __syncthreads();
    short8 af[4], bf[6];
#pragma unroll
    for (int mi = 0; mi < 4; ++mi) {
      int base = (wm * 64 + mi * 16 + l16) * 36 + quad * 8;
      short4v lo = *(const short4v*)(As + base);
      short4v hi = *(const short4v*)(As + base + 4);
      af[mi] = __builtin_shufflevector(lo, hi, 0, 1, 2, 3, 4, 5, 6, 7);
    }
#pragma unroll
    for (int g = 0; g < 3; ++g)
#pragma unroll
      for (int p = 0; p < 2; ++p) {
        int base = (g * 64 + (2 * wn + p) * 16 + l16) * 36 + quad * 8;
        short4v lo = *(const short4v*)(Bs + base);
        short4v hi = *(const short4v*)(Bs + base + 4);
        bf[g * 2 + p] = __builtin_shufflevector(lo, hi, 0, 1, 2, 3, 4, 5, 6, 7);
      }
#pragma unroll
    for (int mi = 0; mi < 4; ++mi)
#pragma unroll
      for (int f = 0; f < 6; ++f)
        acc[mi][f] =
            __builtin_amdgcn_mfma_f32_16x16x32_bf16(af[mi], bf[f], acc[mi][f], 0, 0, 0);
    __syncthreads();
  }
  lstm_epilogue(acc, m0, j0, wm, wn, quad, l16, bias, c0, out);
}

extern "C" void kernel_launch(void* const* d_in, const int* in_sizes, int n_in,
                              void* d_out, int out_size, void* d_ws, size_t ws_size,
                              hipStream_t stream) {
  const float* x    = (const float*)d_in[0];
  const float* h0   = (const float*)d_in[1];
  const float* c0   = (const float*)d_in[2];
  const float* W    = (const float*)d_in[3];
  const float* Wh   = (const float*)d_in[4];
  const float* bias = (const float*)d_in[5];
  float* out = (float*)d_out;

  const size_t needA = (size_t)KTOT * BATCH * 2;  // 48 MB
  const size_t needB = (size_t)KTOT * NG * 2;     // 36 MB
  if (ws_size >= needA + needB) {
    unsigned short* Ap = (unsigned short*)d_ws;
    unsigned short* Bp = Ap + (size_t)KTOT * BATCH;
    pack_a_kernel<<<24576, 256, 0, stream>>>(x, h0, Ap);
    pack_b_kernel<<<18432, 256, 0, stream>>>(W, Wh, Bp);
    gemm_packed_kernel<<<2048, 256, 0, stream>>>(Ap, Bp, bias, c0, out);
  } else {
    gemm_f32_kernel<<<2048, 256, 0, stream>>>(x, h0, W, Wh, bias, c0, out);
  }
}